// Round 8
// baseline (1161.010 us; speedup 1.0000x reference)
//
#include <hip/hip_runtime.h>
#include <hip/hip_cooperative_groups.h>

namespace cg = cooperative_groups;

#define BATCH 8
#define PN    16384
#define NSAMP 256
#define KDIM  512
#define HID   384
#define HALF  192
#define CIN   576   // HID + HALF
#define ROWS  2048  // BATCH * NSAMP
#define BN_EPS 1e-5f

// workspace offsets (in floats)
#define OFF_GF   0
#define OFF_W1T  3072
#define OFF_W2T  224256
#define OFF_IDX  371712   /* 2048 ints */
#define OFF_H1   373760
#define OFF_H2   1160192
#define OFF_SUM1 1946624
#define OFF_SQ1  1947008
#define OFF_SUM2 1947392
#define OFF_SQ2  1947776
// q buffers overlay the H2 region (dead until phase C; FPS is phase A)
#define OFF_QX   1160192
#define OFF_QY   1291264  /* +131072 */
#define OFF_QZ   1422336  /* +262144 */

// One cooperative kernel, 128 blocks x 1024 threads:
//   phase A: FPS (blocks 0-7) + prep (blocks 8-32)   | grid.sync
//   phase B: GEMM1 (16 rows/block) + BN1 sums        | grid.sync
//   phase C: GEMM2 w/ inline BN1 fin + ReLU          | grid.sync
//   phase D: BN2 fin + affine + ReLU -> out
// FPS: q = L^T p PRECOMPUTED into ws (SoA qx/qy/qz), contiguous ownership
// i = t*16+j -> in-loop reload is 12 dwordx4 loads, no transform, no addr math.
// Distances / tiebreak / reduce are bit-identical to the passing R2 kernel.
__global__ __launch_bounds__(1024) void k_all(
    const float* __restrict__ p,  const float* __restrict__ Wc,
    const float* __restrict__ bc, const float* __restrict__ pf,
    const float* __restrict__ Wf, const float* __restrict__ bfe,
    const float* __restrict__ W1, const float* __restrict__ b1,
    const float* __restrict__ g1, const float* __restrict__ be1,
    const float* __restrict__ W2, const float* __restrict__ b2,
    const float* __restrict__ g2, const float* __restrict__ be2,
    float* __restrict__ ws, float* __restrict__ out) {
  cg::grid_group grid = cg::this_grid();
  int blk = blockIdx.x, t = threadIdx.x;

  __shared__ union {
    struct {
      float s[KDIM];
      float Msh[6];
      unsigned long long red[16];
      int far_sh;
    } a;                                      // phase A
    float ct[CIN * 16];                       // phase B staging (36 KB)
    float ht[HID * 16];                       // phase C staging (24 KB)
  } u;
  __shared__ float sA[HID], sB[HID];          // BN scale/shift (C, then D)

  int* idx_out = (int*)(ws + OFF_IDX);

  // ======================= Phase A =======================
  if (blk < 8) {
    // ---- FPS, one batch per block (Mahalanobis rank-3 trick) ----
    int b = blk;
    if (t < 64) {                      // G = Wc Wc^T (fp64) + Cholesky, wave 0
      double g0 = 0, g1d = 0, g2d = 0, g3 = 0, g4 = 0, g5 = 0;
      for (int k = t; k < HALF; k += 64) {
        double w0 = (double)Wc[k];
        double w1 = (double)Wc[HALF + k];
        double w2 = (double)Wc[2 * HALF + k];
        g0 += w0 * w0; g1d += w0 * w1; g2d += w0 * w2;
        g3 += w1 * w1; g4  += w1 * w2; g5  += w2 * w2;
      }
      for (int off = 32; off; off >>= 1) {
        g0 += __shfl_down(g0, off, 64); g1d += __shfl_down(g1d, off, 64);
        g2d += __shfl_down(g2d, off, 64); g3 += __shfl_down(g3, off, 64);
        g4 += __shfl_down(g4, off, 64); g5 += __shfl_down(g5, off, 64);
      }
      if (t == 0) {
        double l00 = sqrt(g0);
        double l10 = g1d / l00, l20 = g2d / l00;
        double l11 = sqrt(g3 - l10 * l10);
        double l21 = (g4 - l10 * l20) / l11;
        double l22 = sqrt(g5 - l20 * l20 - l21 * l21);
        u.a.Msh[0] = (float)l00; u.a.Msh[1] = (float)l10; u.a.Msh[2] = (float)l20;
        u.a.Msh[3] = (float)l11; u.a.Msh[4] = (float)l21; u.a.Msh[5] = (float)l22;
      }
    }
    __syncthreads();
    float m00 = u.a.Msh[0], m10 = u.a.Msh[1], m20 = u.a.Msh[2];
    float m11 = u.a.Msh[3], m21 = u.a.Msh[4], m22 = u.a.Msh[5];

    const float* pb = p + b * PN * 3;
    float* qxp = ws + OFF_QX + b * PN;
    float* qyp = ws + OFF_QY + b * PN;
    float* qzp = ws + OFF_QZ + b * PN;

    // one-time: q = L^T p (same fp expressions as R2 -> bit-identical dists)
    {
      int i0 = t << 4;                 // contiguous ownership: i = t*16 + j
#pragma unroll
      for (int j = 0; j < 16; j++) {
        int i = i0 + j;
        float x = pb[i * 3], y = pb[i * 3 + 1], z = pb[i * 3 + 2];
        qxp[i] = fmaf(m00, x, fmaf(m10, y, m20 * z));
        qyp[i] = fmaf(m11, y, m21 * z);
        qzp[i] = m22 * z;
      }
    }
    __syncthreads();                   // drains vmcnt -> q visible block-wide

    const float4* qx4 = (const float4*)qxp + (t << 2);
    const float4* qy4 = (const float4*)qyp + (t << 2);
    const float4* qz4 = (const float4*)qzp + (t << 2);

    float dist[16];
#pragma unroll
    for (int j = 0; j < 16; j++) dist[j] = 1e10f;

    int far = 0;
    for (int k = 0; k < NSAMP; k++) {
      if (t == 0) idx_out[b * NSAMP + k] = far;  // scan emits pre-update far
      float cx = qxp[far], cy = qyp[far], cz = qzp[far]; // LDS-sourced far
      float bv = -1.f; unsigned bj = 0;
#pragma unroll
      for (int g = 0; g < 4; g++) {
        float4 xv = qx4[g], yv = qy4[g], zv = qz4[g];   // 3 dwordx4 loads
#define ONE(comp, idx) {                                                     \
        float dx = xv.comp - cx, dy = yv.comp - cy, dz = zv.comp - cz;       \
        float dd = fmaf(dx, dx, fmaf(dy, dy, dz * dz));                      \
        float nd = fminf(dist[idx], dd);                                     \
        dist[idx] = nd;                                                      \
        bool gt = nd > bv;                /* strict > : first-index tiebreak */\
        bv = gt ? nd : bv;                                                   \
        bj = gt ? (unsigned)(idx) : bj; }
        ONE(x, 4 * 0 + 0 + 4 * g) ONE(y, 1 + 4 * g)
        ONE(z, 2 + 4 * g)         ONE(w, 3 + 4 * g)
#undef ONE
      }
      unsigned bi = ((unsigned)t << 4) + bj;     // global idx = t*16 + bj
      // pack: larger dist wins; equal dist -> smaller global index wins (~bi)
      unsigned long long key =
          (((unsigned long long)__float_as_uint(bv)) << 32) | (unsigned)(~bi);
#pragma unroll
      for (int off = 32; off; off >>= 1) {       // per-wave butterfly
        unsigned long long o = __shfl_xor(key, off, 64);
        key = (o > key) ? o : key;
      }
      if ((t & 63) == 0) u.a.red[t >> 6] = key;
      __syncthreads();
      if (t < 64) {                              // wave0 reduces the 16 keys
        unsigned long long k2 = (t < 16) ? u.a.red[t] : 0ull;
#pragma unroll
        for (int off = 8; off; off >>= 1) {
          unsigned long long o = __shfl_xor(k2, off, 64);
          k2 = (o > k2) ? o : k2;
        }
        if (t == 0) u.a.far_sh = (int)(~((unsigned)k2));
      }
      __syncthreads();
      far = u.a.far_sh;                          // LDS -> divergent -> vec loads
    }
  } else if (blk < 16) {               // W1t[c][o] = W1[o][c]
    for (int sI = (blk - 8) * 1024 + t; sI < HID * CIN; sI += 8192) {
      int o = sI / CIN, c = sI % CIN;
      ws[OFF_W1T + c * HID + o] = W1[sI];
    }
  } else if (blk < 24) {               // W2t[c][o] = W2[o][c]
    for (int sI = (blk - 16) * 1024 + t; sI < HID * HID; sI += 8192) {
      int o = sI / HID, c = sI % HID;
      ws[OFF_W2T + c * HID + o] = W2[sI];
    }
  } else if (blk < 32) {               // global_feat[b] = pf[b] @ W_feat + b_feat
    int b = blk - 24;
    if (t < KDIM) u.a.s[t] = pf[b * KDIM + t];
    __syncthreads();
    if (t < HID) {
      float acc = bfe[t];
      for (int k = 0; k < KDIM; k++) acc = fmaf(u.a.s[k], Wf[k * HID + t], acc);
      ws[OFF_GF + b * HID + t] = acc;
    }
  } else if (blk == 32) {              // zero BN sums (contiguous 1536 floats)
    for (int i = t; i < 1536; i += 1024) ws[OFF_SUM1 + i] = 0.f;
  }
  grid.sync();

  // ======================= Phase B: GEMM1 + BN1 sums =======================
  {
    int row0 = blk * 16;
    const int* fidx = (const int*)(ws + OFF_IDX);
    for (int sI = t; sI < 16 * CIN; sI += 1024) { // stage transposed ct[c*16+r]
      int r = sI / CIN, c = sI % CIN;
      int row = row0 + r, b = row >> 8;
      float val;
      if (c < HID) {
        val = ws[OFF_GF + b * HID + c];          // broadcast global_feat
      } else {
        int co = c - HID;
        int i = fidx[row];
        const float* pp = p + (b * PN + i) * 3;
        val = bc[co];
        val = fmaf(pp[0], Wc[co], val);
        val = fmaf(pp[1], Wc[HALF + co], val);
        val = fmaf(pp[2], Wc[2 * HALF + co], val);  // sampled local_feat
      }
      u.ct[c * 16 + r] = val;
    }
    __syncthreads();
    if (t < HID) {
      const float* w1t = ws + OFF_W1T;
      float acc[16];
#pragma unroll
      for (int r = 0; r < 16; r++) acc[r] = 0.f;
      for (int c = 0; c < CIN; c++) {
        float w = w1t[c * HID + t];
        const float4* a4 = (const float4*)(u.ct + c * 16);
#pragma unroll
        for (int g = 0; g < 4; g++) {
          float4 a = a4[g];
          acc[4 * g + 0] = fmaf(a.x, w, acc[4 * g + 0]);
          acc[4 * g + 1] = fmaf(a.y, w, acc[4 * g + 1]);
          acc[4 * g + 2] = fmaf(a.z, w, acc[4 * g + 2]);
          acc[4 * g + 3] = fmaf(a.w, w, acc[4 * g + 3]);
        }
      }
      float bias = b1[t];
      float sv = 0.f, sq = 0.f;
#pragma unroll
      for (int r = 0; r < 16; r++) {
        float v = acc[r] + bias;
        ws[OFF_H1 + (row0 + r) * HID + t] = v;
        sv += v; sq = fmaf(v, v, sq);
      }
      atomicAdd(&ws[OFF_SUM1 + t], sv);
      atomicAdd(&ws[OFF_SQ1 + t], sq);
    }
  }
  grid.sync();

  // ============== Phase C: GEMM2, BN1 finalize + ReLU fused on load =========
  {
    int row0 = blk * 16;
    if (t < HID) {                     // BN1 finalize, redundantly per block
      float m = ws[OFF_SUM1 + t] * (1.f / ROWS);
      float v = ws[OFF_SQ1 + t] * (1.f / ROWS) - m * m;
      float sc = (1.f / sqrtf(v + BN_EPS)) * g1[t];
      sA[t] = sc;
      sB[t] = be1[t] - m * sc;
    }
    __syncthreads();
    for (int sI = t; sI < 16 * HID; sI += 1024) {
      int r = sI / HID, c = sI % HID;
      float x = fmaf(ws[OFF_H1 + (row0 + r) * HID + c], sA[c], sB[c]);
      u.ht[c * 16 + r] = fmaxf(x, 0.f);
    }
    __syncthreads();
    if (t < HID) {
      const float* w2t = ws + OFF_W2T;
      float acc[16];
#pragma unroll
      for (int r = 0; r < 16; r++) acc[r] = 0.f;
      for (int c = 0; c < HID; c++) {
        float w = w2t[c * HID + t];
        const float4* a4 = (const float4*)(u.ht + c * 16);
#pragma unroll
        for (int g = 0; g < 4; g++) {
          float4 a = a4[g];
          acc[4 * g + 0] = fmaf(a.x, w, acc[4 * g + 0]);
          acc[4 * g + 1] = fmaf(a.y, w, acc[4 * g + 1]);
          acc[4 * g + 2] = fmaf(a.z, w, acc[4 * g + 2]);
          acc[4 * g + 3] = fmaf(a.w, w, acc[4 * g + 3]);
        }
      }
      float bias = b2[t];
      float sv = 0.f, sq = 0.f;
#pragma unroll
      for (int r = 0; r < 16; r++) {
        float v = acc[r] + bias;
        ws[OFF_H2 + (row0 + r) * HID + t] = v;
        sv += v; sq = fmaf(v, v, sq);
      }
      atomicAdd(&ws[OFF_SUM2 + t], sv);
      atomicAdd(&ws[OFF_SQ2 + t], sq);
    }
  }
  grid.sync();

  // ============== Phase D: BN2 finalize + affine + ReLU ====================
  {
    if (t < HID) {
      float m = ws[OFF_SUM2 + t] * (1.f / ROWS);
      float v = ws[OFF_SQ2 + t] * (1.f / ROWS) - m * m;
      float sc = (1.f / sqrtf(v + BN_EPS)) * g2[t];
      sA[t] = sc;
      sB[t] = be2[t] - m * sc;
    }
    __syncthreads();
    for (int i4 = blk * 1024 + t; i4 < ROWS * HID / 4; i4 += 128 * 1024) {
      int i = i4 * 4;
      int c = i % HID;                 // multiple of 4
      float4 h = *(const float4*)(ws + OFF_H2 + i);
      float4 r;
      r.x = fmaxf(fmaf(h.x, sA[c],     sB[c]),     0.f);
      r.y = fmaxf(fmaf(h.y, sA[c + 1], sB[c + 1]), 0.f);
      r.z = fmaxf(fmaf(h.z, sA[c + 2], sB[c + 2]), 0.f);
      r.w = fmaxf(fmaf(h.w, sA[c + 3], sB[c + 3]), 0.f);
      ((float4*)out)[i4] = r;
    }
  }
}

extern "C" void kernel_launch(void* const* d_in, const int* in_sizes, int n_in,
                              void* d_out, int out_size, void* d_ws, size_t ws_size,
                              hipStream_t stream) {
  const float* p   = (const float*)d_in[0];
  // d_in[1] = N (int scalar, always 256)
  const float* pf  = (const float*)d_in[2];
  const float* Wf  = (const float*)d_in[3];
  const float* bfe = (const float*)d_in[4];
  const float* Wc  = (const float*)d_in[5];
  const float* bc  = (const float*)d_in[6];
  const float* W1  = (const float*)d_in[7];
  const float* b1  = (const float*)d_in[8];
  const float* g1  = (const float*)d_in[9];
  const float* be1 = (const float*)d_in[10];
  const float* W2  = (const float*)d_in[11];
  const float* b2  = (const float*)d_in[12];
  const float* g2  = (const float*)d_in[13];
  const float* be2 = (const float*)d_in[14];
  float* ws  = (float*)d_ws;
  float* out = (float*)d_out;

  void* args[] = {(void*)&p,  (void*)&Wc, (void*)&bc,  (void*)&pf,
                  (void*)&Wf, (void*)&bfe,(void*)&W1,  (void*)&b1,
                  (void*)&g1, (void*)&be1,(void*)&W2,  (void*)&b2,
                  (void*)&g2, (void*)&be2,(void*)&ws,  (void*)&out};
  hipLaunchCooperativeKernel((void*)k_all, dim3(128), dim3(1024), args, 0, stream);
}